// Round 1
// baseline (1039.230 us; speedup 1.0000x reference)
//
#include <hip/hip_runtime.h>
#include <cstdint>
#include <cstddef>

// Problem constants
#define B_SZ  8192
#define IN_SZ 2048
#define H_SZ  2048
#define KC_SZ 4096   // IN + H

typedef unsigned short ushort_t;
typedef __attribute__((ext_vector_type(8))) short bf16x8;   // 8 bf16 = 4 VGPRs
typedef __attribute__((ext_vector_type(4))) float floatx4;  // MFMA C/D

__device__ __forceinline__ ushort_t f2bf(float f) {
  union { float f; unsigned u; } v; v.f = f;
  unsigned u = v.u;
  return (ushort_t)((u + 0x7FFFu + ((u >> 16) & 1u)) >> 16);  // RNE
}

__device__ __forceinline__ void g2lds16(const void* g, void* l) {
  __builtin_amdgcn_global_load_lds(
      (const __attribute__((address_space(1))) unsigned int*)g,
      (__attribute__((address_space(3))) unsigned int*)l, 16, 0, 0);
}

// ---------------------------------------------------------------------------
// prep: concat_input (fp32, exact) + bf16 A into workspace. One float4/thread.
__global__ void prep_concat(const float* __restrict__ in, const float* __restrict__ st,
                            float* __restrict__ cat, ushort_t* __restrict__ Abf) {
  size_t i4 = (size_t)blockIdx.x * blockDim.x + threadIdx.x;  // over B*KC/4
  size_t row  = i4 >> 10;        // / (KC/4)
  size_t col4 = i4 & 1023;
  float4 v;
  if (col4 < (IN_SZ / 4))
    v = ((const float4*)in)[row * (IN_SZ / 4) + col4];
  else
    v = ((const float4*)st)[row * (H_SZ / 4) + (col4 - IN_SZ / 4)];
  ((float4*)cat)[i4] = v;
  union { ushort_t u[4]; uint2 p; } pk;
  pk.u[0] = f2bf(v.x); pk.u[1] = f2bf(v.y); pk.u[2] = f2bf(v.z); pk.u[3] = f2bf(v.w);
  ((uint2*)Abf)[i4] = pk.p;
}

// bf16 casts of gate_weights [H,KC] and weights_i [H,IN]
__global__ void prep_weights(const float* __restrict__ gw, const float* __restrict__ wi,
                             ushort_t* __restrict__ Wg, ushort_t* __restrict__ Wi) {
  size_t i4 = (size_t)blockIdx.x * blockDim.x + threadIdx.x;
  const size_t n1 = (size_t)H_SZ * KC_SZ / 4;
  union { ushort_t u[4]; uint2 p; } pk;
  if (i4 < n1) {
    float4 v = ((const float4*)gw)[i4];
    pk.u[0] = f2bf(v.x); pk.u[1] = f2bf(v.y); pk.u[2] = f2bf(v.z); pk.u[3] = f2bf(v.w);
    ((uint2*)Wg)[i4] = pk.p;
  } else {
    size_t j = i4 - n1;
    float4 v = ((const float4*)wi)[j];
    pk.u[0] = f2bf(v.x); pk.u[1] = f2bf(v.y); pk.u[2] = f2bf(v.z); pk.u[3] = f2bf(v.w);
    ((uint2*)Wi)[j] = pk.p;
  }
}

// ---------------------------------------------------------------------------
// Fused dual-accumulator GEMM:
//   acc_gate = A[128,4096] x Wg[64,4096]^T   (K = KC)
//   acc_val  = A[128,0:2048] x Wi[64,2048]^T (K = IN; A's input half)
// BM=128, BN=64, BK=64, 256 threads = 4 waves, each wave a 64x32 sub-tile of
// BOTH outputs via 4x2 16x16x32 MFMA pairs. Full epilogue chain in-register:
//   pre_gate = acc_gate + bias; gate = clip(pre_gate,0,1); values = tanh(acc_val)
//   pre_h = state*(1-gate) + values*gate; new_h = relu(pre_h)
// Removes the entire second GEMM pass: no gate write+re-read round-trip
// (134 MB), no duplicate A staging for the K=2048 panel, one launch fewer.
__global__ __launch_bounds__(256) void gemm_fused(
    const ushort_t* __restrict__ A, const ushort_t* __restrict__ Wg,
    const ushort_t* __restrict__ Wi, const float* __restrict__ gb,
    const float* __restrict__ st,
    float* __restrict__ pre_gate, float* __restrict__ gate,
    float* __restrict__ values, float* __restrict__ pre_h,
    float* __restrict__ new_h) {
  constexpr int BM = 128, BN = 64, BK = 64;
  __shared__ __align__(16) ushort_t sA[BM * BK];   // 16 KiB
  __shared__ __align__(16) ushort_t sG[BN * BK];   //  8 KiB
  __shared__ __align__(16) ushort_t sV[BN * BK];   //  8 KiB

  const int tid  = threadIdx.x;
  const int lane = tid & 63;
  const int quad = lane >> 4;
  const int l16  = lane & 15;
  const int wm   = ((tid >> 6) >> 1) * 64;   // wave row offset (0/64)
  const int wn   = ((tid >> 6) & 1) * 32;    // wave col offset (0/32)

  const int nTiles = H_SZ / BN;              // 32
  const int row0 = (blockIdx.x / nTiles) * BM;
  const int col0 = (blockIdx.x % nTiles) * BN;

  floatx4 ag[4][2] = {};   // gate accumulator
  floatx4 av[4][2] = {};   // value accumulator

  const ushort_t* Ab = A  + (size_t)row0 * KC_SZ;
  const ushort_t* Gp = Wg + (size_t)col0 * KC_SZ;
  const ushort_t* Vp = Wi + (size_t)col0 * IN_SZ;
  const int ldsbase = (tid & 192) * 8;       // wave-uniform LDS dest base

  // ---- phase 1: k in [0, IN) — feed both accumulators -------------------
  int k0 = 0;
  for (; k0 < IN_SZ; k0 += BK) {
#pragma unroll
    for (int it = 0; it < 4; ++it) {         // A: 128x64 bf16 = 1024 chunks
      int chunk = it * 256 + tid;
      int r = chunk >> 3, c = (chunk & 7) << 3;
      g2lds16(Ab + (size_t)r * KC_SZ + (k0 + c), &sA[it * 2048 + ldsbase]);
    }
#pragma unroll
    for (int it = 0; it < 2; ++it) {         // Wg: 64x64 = 512 chunks
      int chunk = it * 256 + tid;
      int r = chunk >> 3, c = (chunk & 7) << 3;
      g2lds16(Gp + (size_t)r * KC_SZ + (k0 + c), &sG[it * 2048 + ldsbase]);
    }
#pragma unroll
    for (int it = 0; it < 2; ++it) {         // Wi: 64x64 = 512 chunks
      int chunk = it * 256 + tid;
      int r = chunk >> 3, c = (chunk & 7) << 3;
      g2lds16(Vp + (size_t)r * IN_SZ + (k0 + c), &sV[it * 2048 + ldsbase]);
    }
    __syncthreads();
#pragma unroll
    for (int ks = 0; ks < BK; ks += 32) {
      bf16x8 af[4], bg[2], bv[2];
#pragma unroll
      for (int i = 0; i < 4; ++i)
        af[i] = *(const bf16x8*)&sA[(wm + i * 16 + l16) * BK + ks + quad * 8];
#pragma unroll
      for (int j = 0; j < 2; ++j) {
        bg[j] = *(const bf16x8*)&sG[(wn + j * 16 + l16) * BK + ks + quad * 8];
        bv[j] = *(const bf16x8*)&sV[(wn + j * 16 + l16) * BK + ks + quad * 8];
      }
#pragma unroll
      for (int i = 0; i < 4; ++i)
#pragma unroll
        for (int j = 0; j < 2; ++j) {
          ag[i][j] = __builtin_amdgcn_mfma_f32_16x16x32_bf16(af[i], bg[j], ag[i][j], 0, 0, 0);
          av[i][j] = __builtin_amdgcn_mfma_f32_16x16x32_bf16(af[i], bv[j], av[i][j], 0, 0, 0);
        }
    }
    __syncthreads();
  }

  // ---- phase 2: k in [IN, KC) — gate accumulator only -------------------
  for (; k0 < KC_SZ; k0 += BK) {
#pragma unroll
    for (int it = 0; it < 4; ++it) {
      int chunk = it * 256 + tid;
      int r = chunk >> 3, c = (chunk & 7) << 3;
      g2lds16(Ab + (size_t)r * KC_SZ + (k0 + c), &sA[it * 2048 + ldsbase]);
    }
#pragma unroll
    for (int it = 0; it < 2; ++it) {
      int chunk = it * 256 + tid;
      int r = chunk >> 3, c = (chunk & 7) << 3;
      g2lds16(Gp + (size_t)r * KC_SZ + (k0 + c), &sG[it * 2048 + ldsbase]);
    }
    __syncthreads();
#pragma unroll
    for (int ks = 0; ks < BK; ks += 32) {
      bf16x8 af[4], bg[2];
#pragma unroll
      for (int i = 0; i < 4; ++i)
        af[i] = *(const bf16x8*)&sA[(wm + i * 16 + l16) * BK + ks + quad * 8];
#pragma unroll
      for (int j = 0; j < 2; ++j)
        bg[j] = *(const bf16x8*)&sG[(wn + j * 16 + l16) * BK + ks + quad * 8];
#pragma unroll
      for (int i = 0; i < 4; ++i)
#pragma unroll
        for (int j = 0; j < 2; ++j)
          ag[i][j] = __builtin_amdgcn_mfma_f32_16x16x32_bf16(af[i], bg[j], ag[i][j], 0, 0, 0);
    }
    __syncthreads();
  }

  // ---- epilogue. C/D layout: col = lane&15, row = quad*4 + reg ----------
  float bj[2];
#pragma unroll
  for (int j = 0; j < 2; ++j) bj[j] = gb[col0 + wn + j * 16 + l16];
#pragma unroll
  for (int i = 0; i < 4; ++i) {
    int rbase = row0 + wm + i * 16 + quad * 4;
#pragma unroll
    for (int j = 0; j < 2; ++j) {
      int col = col0 + wn + j * 16 + l16;
#pragma unroll
      for (int r = 0; r < 4; ++r) {
        size_t idx = (size_t)(rbase + r) * H_SZ + col;
        float pre = ag[i][j][r] + bj[j];
        float g   = fminf(fmaxf(pre, 0.f), 1.f);
        float v   = tanhf(av[i][j][r]);
        float s   = st[idx];
        float ph  = s * (1.f - g) + v * g;
        pre_gate[idx] = pre;
        gate[idx]     = g;
        values[idx]   = v;
        pre_h[idx]    = ph;
        new_h[idx]    = fmaxf(ph, 0.f);
      }
    }
  }
}

// ---------------------------------------------------------------------------
// Fallback (only if ws_size < 88 MiB): naive fp32, correct but slow.
__global__ void concat_only(const float* __restrict__ in, const float* __restrict__ st,
                            float* __restrict__ cat) {
  size_t i4 = (size_t)blockIdx.x * blockDim.x + threadIdx.x;
  size_t row = i4 >> 10, col4 = i4 & 1023;
  float4 v;
  if (col4 < (IN_SZ / 4))
    v = ((const float4*)in)[row * (IN_SZ / 4) + col4];
  else
    v = ((const float4*)st)[row * (H_SZ / 4) + (col4 - IN_SZ / 4)];
  ((float4*)cat)[i4] = v;
}

__global__ void naive_all(const float* __restrict__ in, const float* __restrict__ st,
                          const float* __restrict__ gw, const float* __restrict__ gb,
                          const float* __restrict__ wi,
                          float* __restrict__ new_h, float* __restrict__ pre_gate,
                          float* __restrict__ gate, float* __restrict__ values,
                          float* __restrict__ pre_h) {
  size_t idx = (size_t)blockIdx.x * blockDim.x + threadIdx.x;
  if (idx >= (size_t)B_SZ * H_SZ) return;
  int b = (int)(idx / H_SZ), h = (int)(idx % H_SZ);
  const float* wgr = gw + (size_t)h * KC_SZ;
  const float* wir = wi + (size_t)h * IN_SZ;
  const float* x = in + (size_t)b * IN_SZ;
  const float* s = st + (size_t)b * H_SZ;
  float ag = 0.f, av = 0.f;
  for (int c = 0; c < IN_SZ; ++c) { float a = x[c]; ag += a * wgr[c]; av += a * wir[c]; }
  for (int c = 0; c < H_SZ; ++c) ag += s[c] * wgr[IN_SZ + c];
  float pre = ag + gb[h];
  float g = fminf(fmaxf(pre, 0.f), 1.f);
  float v = tanhf(av);
  float ph = s[h] * (1.f - g) + v * g;
  pre_gate[idx] = pre; gate[idx] = g; values[idx] = v;
  pre_h[idx] = ph; new_h[idx] = fmaxf(ph, 0.f);
}

// ---------------------------------------------------------------------------
extern "C" void kernel_launch(void* const* d_in, const int* in_sizes, int n_in,
                              void* d_out, int out_size, void* d_ws, size_t ws_size,
                              hipStream_t stream) {
  const float* input = (const float*)d_in[0];
  const float* state = (const float*)d_in[1];
  const float* gw    = (const float*)d_in[2];
  const float* gb    = (const float*)d_in[3];
  const float* wi    = (const float*)d_in[4];

  float* out      = (float*)d_out;
  float* new_h    = out;                                   // [B,H]
  float* cat      = new_h + (size_t)B_SZ * H_SZ;           // [B,KC]
  float* pre_gate = cat + (size_t)B_SZ * KC_SZ;            // [B,H]
  float* gate     = pre_gate + (size_t)B_SZ * H_SZ;        // [B,H]
  float* values   = gate + (size_t)B_SZ * H_SZ;            // [B,H]
  float* pre_h    = values + (size_t)B_SZ * H_SZ;          // [B,H]

  const size_t needA  = (size_t)B_SZ * KC_SZ * 2;   // 64 MiB
  const size_t needWg = (size_t)H_SZ * KC_SZ * 2;   // 16 MiB
  const size_t needWi = (size_t)H_SZ * IN_SZ * 2;   //  8 MiB
  if (ws_size >= needA + needWg + needWi) {
    ushort_t* Abf  = (ushort_t*)d_ws;
    ushort_t* Wgbf = Abf + (size_t)B_SZ * KC_SZ;
    ushort_t* Wibf = Wgbf + (size_t)H_SZ * KC_SZ;

    prep_concat<<<dim3((B_SZ * (size_t)KC_SZ / 4) / 256), dim3(256), 0, stream>>>(
        input, state, cat, Abf);
    prep_weights<<<dim3(((size_t)H_SZ * KC_SZ / 4 + (size_t)H_SZ * IN_SZ / 4) / 256),
                   dim3(256), 0, stream>>>(gw, wi, Wgbf, Wibf);

    const int grid = (B_SZ / 128) * (H_SZ / 64);  // 64 * 32 = 2048
    gemm_fused<<<dim3(grid), dim3(256), 0, stream>>>(
        Abf, Wgbf, Wibf, gb, state, pre_gate, gate, values, pre_h, new_h);
  } else {
    concat_only<<<dim3((B_SZ * (size_t)KC_SZ / 4) / 256), dim3(256), 0, stream>>>(
        input, state, cat);
    naive_all<<<dim3((B_SZ * (size_t)H_SZ + 255) / 256), dim3(256), 0, stream>>>(
        input, state, gw, gb, wi, new_h, pre_gate, gate, values, pre_h);
  }
}

// Round 2
// 871.923 us; speedup vs baseline: 1.1919x; 1.1919x over previous
//
#include <hip/hip_runtime.h>
#include <cstdint>
#include <cstddef>

// Problem constants
#define B_SZ  8192
#define IN_SZ 2048
#define H_SZ  2048
#define KC_SZ 4096   // IN + H

typedef unsigned short ushort_t;
typedef __attribute__((ext_vector_type(8))) short bf16x8;   // 8 bf16 = 4 VGPRs
typedef __attribute__((ext_vector_type(4))) float floatx4;  // MFMA C/D

__device__ __forceinline__ ushort_t f2bf(float f) {
  union { float f; unsigned u; } v; v.f = f;
  unsigned u = v.u;
  return (ushort_t)((u + 0x7FFFu + ((u >> 16) & 1u)) >> 16);  // RNE
}

__device__ __forceinline__ void g2lds16(const void* g, void* l) {
  __builtin_amdgcn_global_load_lds(
      (const __attribute__((address_space(1))) unsigned int*)g,
      (__attribute__((address_space(3))) unsigned int*)l, 16, 0, 0);
}

// ---------------------------------------------------------------------------
// prep: concat_input (fp32, exact) + bf16 A into workspace. One float4/thread.
__global__ void prep_concat(const float* __restrict__ in, const float* __restrict__ st,
                            float* __restrict__ cat, ushort_t* __restrict__ Abf) {
  size_t i4 = (size_t)blockIdx.x * blockDim.x + threadIdx.x;  // over B*KC/4
  size_t row  = i4 >> 10;        // / (KC/4)
  size_t col4 = i4 & 1023;
  float4 v;
  if (col4 < (IN_SZ / 4))
    v = ((const float4*)in)[row * (IN_SZ / 4) + col4];
  else
    v = ((const float4*)st)[row * (H_SZ / 4) + (col4 - IN_SZ / 4)];
  ((float4*)cat)[i4] = v;
  union { ushort_t u[4]; uint2 p; } pk;
  pk.u[0] = f2bf(v.x); pk.u[1] = f2bf(v.y); pk.u[2] = f2bf(v.z); pk.u[3] = f2bf(v.w);
  ((uint2*)Abf)[i4] = pk.p;
}

// bf16 casts of gate_weights [H,KC] and weights_i [H,IN]
__global__ void prep_weights(const float* __restrict__ gw, const float* __restrict__ wi,
                             ushort_t* __restrict__ Wg, ushort_t* __restrict__ Wi) {
  size_t i4 = (size_t)blockIdx.x * blockDim.x + threadIdx.x;
  const size_t n1 = (size_t)H_SZ * KC_SZ / 4;
  union { ushort_t u[4]; uint2 p; } pk;
  if (i4 < n1) {
    float4 v = ((const float4*)gw)[i4];
    pk.u[0] = f2bf(v.x); pk.u[1] = f2bf(v.y); pk.u[2] = f2bf(v.z); pk.u[3] = f2bf(v.w);
    ((uint2*)Wg)[i4] = pk.p;
  } else {
    size_t j = i4 - n1;
    float4 v = ((const float4*)wi)[j];
    pk.u[0] = f2bf(v.x); pk.u[1] = f2bf(v.y); pk.u[2] = f2bf(v.z); pk.u[3] = f2bf(v.w);
    ((uint2*)Wi)[j] = pk.p;
  }
}

// ---------------------------------------------------------------------------
// Deep-pipelined bf16 GEMM, C = A (row-major, lda) x W^T (row-major, ldw), N=2048.
// BM=BN=256, BK=32, 512 threads = 8 waves (2M x 4N), per-wave 128x64 out.
// 4-deep LDS ring (4 x 32 KiB): compute tile t from buf t%4 while issuing
// tile t+3 into buf (t+3)%4 (last read by tile t-1, already behind a barrier
// -> no write-while-read). Counted vmcnt(8) at tile boundary keeps 2 tiles
// in flight (T4, never drain-0 in steady state). st_16x32 XOR swizzle via
// pre-swizzled GLOBAL source + swizzled ds_read (linear LDS dest; rule #21).
// Raw s_barrier only (no __syncthreads -> no vmcnt(0) drain). setprio around
// the MFMA cluster (T5). Accumulation order over K identical to the verified
// round-0 kernel -> bit-identical outputs.
// EPI=0: gate epilogue  (o0=pre_gate, o1=gate, x0=bias)
// EPI=1: value epilogue (o0=values, o1=pre_h, o2=new_h, x0=gate, x1=state)
template <int EPI>
__global__ __launch_bounds__(512, 2) void gemm_pipe(
    const ushort_t* __restrict__ A, const ushort_t* __restrict__ W,
    int K, int lda, int ldw,
    float* __restrict__ o0, float* __restrict__ o1, float* __restrict__ o2,
    const float* __restrict__ x0, const float* __restrict__ x1) {
  constexpr int BM = 256, BN = 256, BK = 32;
  constexpr int TILE_US = (BM + BN) * BK;                 // 16384 ushorts / buffer
  __shared__ __align__(16) ushort_t lds[4 * TILE_US];     // 128 KiB

  const int tid  = threadIdx.x;
  const int lane = tid & 63;
  const int w    = tid >> 6;          // wave 0..7
  const int quad = lane >> 4;
  const int l16  = lane & 15;
  const int wm   = (w >> 2) * 128;    // wave row offset (2M)
  const int wn   = (w & 3) * 64;      // wave col offset (4N)

  const int row0 = (blockIdx.x >> 3) * BM;   // grid = 32 x 8
  const int col0 = (blockIdx.x & 7) * BN;

  const int NT = K / BK;

  // --- staging setup: waves 0-3 stage A subtiles, waves 4-7 stage B -------
  // A tile 256x32 = 16 subtiles of [16][32] bf16 (1 KiB each); B likewise.
  // Subtile s: wave (w&3) handles s = (w&3)*4 + q, q=0..3.
  // One global_load_lds fills one subtile: lane l writes bytes [16l,16l+16)
  // -> row r=l>>2, phys cols (l&3)*8..+8. Pre-swizzle: logical col =
  // phys ^ ((r>>3)<<4), so lane loads global cols cl = ((l&3)*8) ^ ((l>>5)<<4).
  const int rl = lane >> 2;
  const int cl = ((lane & 3) << 3) ^ (((lane >> 5) & 1) << 4);
  const bool isA = (w < 4);
  const ushort_t* gbase = isA ? (A + (size_t)row0 * lda) : (W + (size_t)col0 * ldw);
  const int ld = isA ? lda : ldw;
  const int Rbase = (w & 3) * 4;
  const size_t laneRowOff = (size_t)(Rbase * 16 + rl) * ld + cl;
  const size_t ld16 = (size_t)ld * 16;
  const int ldsSub = (isA ? 0 : BM * BK) + Rbase * 512;   // elements

  floatx4 acc[8][4] = {};

  // --- prologue: stage tiles 0,1,2 (12 issues/wave) ----------------------
  for (int tt = 0; tt < 3; ++tt) {
#pragma unroll
    for (int q = 0; q < 4; ++q) {
      const ushort_t* src = gbase + laneRowOff + (size_t)q * ld16 + (size_t)tt * BK;
      g2lds16(src, &lds[(tt & 3) * TILE_US + ldsSub + q * 512]);
    }
  }
  asm volatile("s_waitcnt vmcnt(8)" ::: "memory");   // tile 0 landed (own wave)
  __builtin_amdgcn_sched_barrier(0);
  __builtin_amdgcn_s_barrier();                      // -> all waves' tile 0 landed

  // swizzled ds_read address: logical (row, k=quad*8) -> phys col ^ ((r>>3)<<4)
  const int cp = (quad << 3) ^ ((l16 >> 3) << 4);    // r == l16 for frag reads
  const int fragBase = l16 * 32 + cp;                // per-lane element offset

  for (int t = 0; t < NT; ++t) {
    const ushort_t* bufA = &lds[(t & 3) * TILE_US];
    const ushort_t* bufB = bufA + BM * BK;
    const bool pf = (t + 3 < NT);
    bf16x8 bfr[4];
#pragma unroll
    for (int p = 0; p < 4; ++p) {
      // 1. stage one subtile of tile t+3 (issue-early; lands >= 2 tiles later)
      if (pf) {
        const ushort_t* src = gbase + laneRowOff + (size_t)p * ld16 + (size_t)(t + 3) * BK;
        g2lds16(src, &lds[((t + 3) & 3) * TILE_US + ldsSub + p * 512]);
      }
      // 2. fragment ds_reads (compiler inserts lgkmcnt before MFMA use)
      if (p == 0) {
#pragma unroll
        for (int j = 0; j < 4; ++j)
          bfr[j] = *(const bf16x8*)&bufB[((wn >> 4) + j) * 512 + fragBase];
      }
      bf16x8 a0 = *(const bf16x8*)&bufA[((wm >> 4) + 2 * p) * 512 + fragBase];
      bf16x8 a1 = *(const bf16x8*)&bufA[((wm >> 4) + 2 * p + 1) * 512 + fragBase];
      // 3. MFMA cluster
      __builtin_amdgcn_s_setprio(1);
#pragma unroll
      for (int j = 0; j < 4; ++j) {
        acc[2 * p][j]     = __builtin_amdgcn_mfma_f32_16x16x32_bf16(a0, bfr[j], acc[2 * p][j], 0, 0, 0);
        acc[2 * p + 1][j] = __builtin_amdgcn_mfma_f32_16x16x32_bf16(a1, bfr[j], acc[2 * p + 1][j], 0, 0, 0);
      }
      __builtin_amdgcn_s_setprio(0);
      // 4. phase boundary
      if (p < 3) {
        __builtin_amdgcn_s_barrier();
      } else {
        const int rem = NT - 1 - t;
        if (rem >= 3)      asm volatile("s_waitcnt vmcnt(8)" ::: "memory"); // t+1 landed, t+2/t+3 in flight
        else if (rem == 2) asm volatile("s_waitcnt vmcnt(4)" ::: "memory");
        else if (rem == 1) asm volatile("s_waitcnt vmcnt(0)" ::: "memory");
        __builtin_amdgcn_sched_barrier(0);
        __builtin_amdgcn_s_barrier();
      }
    }
  }

  // --- epilogue. C/D layout: col = lane&15, row = quad*4 + reg -----------
  if (EPI == 0) {
    float bj[4];
#pragma unroll
    for (int j = 0; j < 4; ++j) bj[j] = x0[col0 + wn + j * 16 + l16];
#pragma unroll
    for (int i = 0; i < 8; ++i) {
      int rbase = row0 + wm + i * 16 + quad * 4;
#pragma unroll
      for (int j = 0; j < 4; ++j) {
        int col = col0 + wn + j * 16 + l16;
#pragma unroll
        for (int r = 0; r < 4; ++r) {
          size_t idx = (size_t)(rbase + r) * H_SZ + col;
          float pre = acc[i][j][r] + bj[j];
          o0[idx] = pre;
          o1[idx] = fminf(fmaxf(pre, 0.f), 1.f);
        }
      }
    }
  } else {
#pragma unroll
    for (int i = 0; i < 8; ++i) {
      int rbase = row0 + wm + i * 16 + quad * 4;
#pragma unroll
      for (int j = 0; j < 4; ++j) {
        int col = col0 + wn + j * 16 + l16;
#pragma unroll
        for (int r = 0; r < 4; ++r) {
          size_t idx = (size_t)(rbase + r) * H_SZ + col;
          float v  = tanhf(acc[i][j][r]);
          float g  = x0[idx];
          float s  = x1[idx];
          float ph = s * (1.f - g) + v * g;
          o0[idx] = v;
          o1[idx] = ph;
          o2[idx] = fmaxf(ph, 0.f);
        }
      }
    }
  }
}

// ---------------------------------------------------------------------------
// Fallback (only if ws_size < 88 MiB): naive fp32, correct but slow.
__global__ void concat_only(const float* __restrict__ in, const float* __restrict__ st,
                            float* __restrict__ cat) {
  size_t i4 = (size_t)blockIdx.x * blockDim.x + threadIdx.x;
  size_t row = i4 >> 10, col4 = i4 & 1023;
  float4 v;
  if (col4 < (IN_SZ / 4))
    v = ((const float4*)in)[row * (IN_SZ / 4) + col4];
  else
    v = ((const float4*)st)[row * (H_SZ / 4) + (col4 - IN_SZ / 4)];
  ((float4*)cat)[i4] = v;
}

__global__ void naive_all(const float* __restrict__ in, const float* __restrict__ st,
                          const float* __restrict__ gw, const float* __restrict__ gb,
                          const float* __restrict__ wi,
                          float* __restrict__ new_h, float* __restrict__ pre_gate,
                          float* __restrict__ gate, float* __restrict__ values,
                          float* __restrict__ pre_h) {
  size_t idx = (size_t)blockIdx.x * blockDim.x + threadIdx.x;
  if (idx >= (size_t)B_SZ * H_SZ) return;
  int b = (int)(idx / H_SZ), h = (int)(idx % H_SZ);
  const float* wgr = gw + (size_t)h * KC_SZ;
  const float* wir = wi + (size_t)h * IN_SZ;
  const float* x = in + (size_t)b * IN_SZ;
  const float* s = st + (size_t)b * H_SZ;
  float ag = 0.f, av = 0.f;
  for (int c = 0; c < IN_SZ; ++c) { float a = x[c]; ag += a * wgr[c]; av += a * wir[c]; }
  for (int c = 0; c < H_SZ; ++c) ag += s[c] * wgr[IN_SZ + c];
  float pre = ag + gb[h];
  float g = fminf(fmaxf(pre, 0.f), 1.f);
  float v = tanhf(av);
  float ph = s[h] * (1.f - g) + v * g;
  pre_gate[idx] = pre; gate[idx] = g; values[idx] = v;
  pre_h[idx] = ph; new_h[idx] = fmaxf(ph, 0.f);
}

// ---------------------------------------------------------------------------
extern "C" void kernel_launch(void* const* d_in, const int* in_sizes, int n_in,
                              void* d_out, int out_size, void* d_ws, size_t ws_size,
                              hipStream_t stream) {
  const float* input = (const float*)d_in[0];
  const float* state = (const float*)d_in[1];
  const float* gw    = (const float*)d_in[2];
  const float* gb    = (const float*)d_in[3];
  const float* wi    = (const float*)d_in[4];

  float* out      = (float*)d_out;
  float* new_h    = out;                                   // [B,H]
  float* cat      = new_h + (size_t)B_SZ * H_SZ;           // [B,KC]
  float* pre_gate = cat + (size_t)B_SZ * KC_SZ;            // [B,H]
  float* gate     = pre_gate + (size_t)B_SZ * H_SZ;        // [B,H]
  float* values   = gate + (size_t)B_SZ * H_SZ;            // [B,H]
  float* pre_h    = values + (size_t)B_SZ * H_SZ;          // [B,H]

  const size_t needA  = (size_t)B_SZ * KC_SZ * 2;   // 64 MiB
  const size_t needWg = (size_t)H_SZ * KC_SZ * 2;   // 16 MiB
  const size_t needWi = (size_t)H_SZ * IN_SZ * 2;   //  8 MiB
  if (ws_size >= needA + needWg + needWi) {
    ushort_t* Abf  = (ushort_t*)d_ws;
    ushort_t* Wgbf = Abf + (size_t)B_SZ * KC_SZ;
    ushort_t* Wibf = Wgbf + (size_t)H_SZ * KC_SZ;

    prep_concat<<<dim3((B_SZ * (size_t)KC_SZ / 4) / 256), dim3(256), 0, stream>>>(
        input, state, cat, Abf);
    prep_weights<<<dim3(((size_t)H_SZ * KC_SZ / 4 + (size_t)H_SZ * IN_SZ / 4) / 256),
                   dim3(256), 0, stream>>>(gw, wi, Wgbf, Wibf);

    const int grid = (B_SZ / 256) * (H_SZ / 256);  // 32 * 8 = 256 = 1 block/CU
    gemm_pipe<0><<<dim3(grid), dim3(512), 0, stream>>>(
        Abf, Wgbf, KC_SZ, KC_SZ, KC_SZ, pre_gate, gate, nullptr, gb, nullptr);
    gemm_pipe<1><<<dim3(grid), dim3(512), 0, stream>>>(
        Abf, Wibf, IN_SZ, KC_SZ, IN_SZ, values, pre_h, new_h, gate, state);
  } else {
    concat_only<<<dim3((B_SZ * (size_t)KC_SZ / 4) / 256), dim3(256), 0, stream>>>(
        input, state, cat);
    naive_all<<<dim3((B_SZ * (size_t)H_SZ + 255) / 256), dim3(256), 0, stream>>>(
        input, state, gw, gb, wi, new_h, pre_gate, gate, values, pre_h);
  }
}